// Round 5
// baseline (603.649 us; speedup 1.0000x reference)
//
#include <hip/hip_runtime.h>
#include <hip/hip_fp16.h>
#include <math.h>

#define N_NODES 100000
#define DIM 64
#define E_REL 1600000
#define E_QQ 1000000

#define NBUCK 196      // ceil(100000 / 512) node buckets of 512
#define BCAP 9216      // capacity per bucket; expected 8192, +11 sigma slack
#define CHUNK_E 4096   // edges per phase-1 block -> 391 blocks (occupancy)
#define P1_BLOCKS ((E_REL + CHUNK_E - 1) / CHUNK_E)
#define AGG_BLOCKS 2048          // persistent grid-stride blocks for gather kernels
#define AGG_STRIDE (AGG_BLOCKS * 8)  // 4 waves x 2 nodes per block iteration

// ---------------------------------------------------------------------------
// Phase 1: bin edges by dst-bucket (packed (dlocal<<17)|src) and by src-bucket
// (raw src). Per-block LDS counts; ~2*NBUCK global atomics per block reserve
// space; placement via LDS cursors. int4-vectorized edge reads.
// ---------------------------------------------------------------------------
__global__ __launch_bounds__(256) void bin_edges(
    const int* __restrict__ src, const int* __restrict__ dst,
    int* __restrict__ gcur_d, int* __restrict__ gcur_s,
    unsigned* __restrict__ bin_d, unsigned* __restrict__ bin_s) {
  __shared__ int cd[NBUCK];
  __shared__ int cs[NBUCK];
  int t = threadIdx.x;
  for (int i = t; i < NBUCK; i += 256) { cd[i] = 0; cs[i] = 0; }
  __syncthreads();
  int e0 = blockIdx.x * CHUNK_E;
  int n = E_REL - e0;
  if (n > CHUNK_E) n = CHUNK_E;
  int n4 = n >> 2;  // chunk sizes (4096 / 2560 tail) are multiples of 4
  const int4* s4 = (const int4*)(src + e0);
  const int4* d4 = (const int4*)(dst + e0);
  for (int i = t; i < n4; i += 256) {
    int4 dv = d4[i];
    atomicAdd(&cd[dv.x >> 9], 1);
    atomicAdd(&cd[dv.y >> 9], 1);
    atomicAdd(&cd[dv.z >> 9], 1);
    atomicAdd(&cd[dv.w >> 9], 1);
    int4 sv = s4[i];
    atomicAdd(&cs[sv.x >> 9], 1);
    atomicAdd(&cs[sv.y >> 9], 1);
    atomicAdd(&cs[sv.z >> 9], 1);
    atomicAdd(&cs[sv.w >> 9], 1);
  }
  __syncthreads();
  for (int i = t; i < NBUCK; i += 256) {
    int c = cd[i];
    cd[i] = c > 0 ? atomicAdd(&gcur_d[i], c) : 0;
    c = cs[i];
    cs[i] = c > 0 ? atomicAdd(&gcur_s[i], c) : 0;
  }
  __syncthreads();
  for (int i = t; i < n4; i += 256) {
    int4 sv = s4[i];
    int4 dv = d4[i];
#pragma unroll
    for (int k = 0; k < 4; k++) {
      int s = (&sv.x)[k];
      int d = (&dv.x)[k];
      int bd = d >> 9;
      int bs = s >> 9;
      int pd = atomicAdd(&cd[bd], 1);
      int ps = atomicAdd(&cs[bs], 1);
      if ((unsigned)pd < BCAP)
        bin_d[(size_t)bd * BCAP + pd] = (unsigned)(((d & 511) << 17) | s);
      if ((unsigned)ps < BCAP)
        bin_s[(size_t)bs * BCAP + ps] = (unsigned)s;
    }
  }
}

// ---------------------------------------------------------------------------
// Phase 2 fused: blocks 0..NBUCK-1 build the dst-CSR (histogram -> scan ->
// compact per-node src lists + offs/deg); blocks NBUCK..2*NBUCK-1 build the
// src-degree norm table csrc = rsqrt(outdeg).
// ---------------------------------------------------------------------------
__global__ __launch_bounds__(256) void build_tables(
    const unsigned* __restrict__ bin_d, const int* __restrict__ gcur_d,
    const unsigned* __restrict__ bin_s, const int* __restrict__ gcur_s,
    int* __restrict__ offs, int* __restrict__ degv, int* __restrict__ srclist,
    float* __restrict__ csrc) {
  __shared__ int cnt[512];
  __shared__ int off0[512];
  __shared__ int curv[512];
  __shared__ int ls[256];
  int t = threadIdx.x;
  if (blockIdx.x >= NBUCK) {
    // ---- src histogram -> csrc ----
    int b = blockIdx.x - NBUCK;
    cnt[t] = 0;
    cnt[t + 256] = 0;
    __syncthreads();
    int n = gcur_s[b];
    if (n > BCAP) n = BCAP;
    const unsigned* be = bin_s + (size_t)b * BCAP;
    for (int i = t; i < n; i += 256) atomicAdd(&cnt[be[i] & 511], 1);
    __syncthreads();
    int node0 = b << 9;
    for (int i = t; i < 512; i += 256) {
      int node = node0 + i;
      if (node < N_NODES) {
        int d = cnt[i];
        csrc[node] = d > 0 ? rsqrtf((float)d) : 0.0f;
      }
    }
    return;
  }
  // ---- dst CSR ----
  int b = blockIdx.x;
  cnt[t] = 0;
  cnt[t + 256] = 0;
  __syncthreads();
  int n = gcur_d[b];
  if (n > BCAP) n = BCAP;
  const unsigned* be = bin_d + (size_t)b * BCAP;
  for (int i = t; i < n; i += 256) atomicAdd(&cnt[be[i] >> 17], 1);
  __syncthreads();
  int c0 = cnt[2 * t], c1 = cnt[2 * t + 1];
  ls[t] = c0 + c1;
  __syncthreads();
  for (int off = 1; off < 256; off <<= 1) {
    int v = (t >= off) ? ls[t - off] : 0;
    __syncthreads();
    ls[t] += v;
    __syncthreads();
  }
  int base = ls[t] - (c0 + c1);
  off0[2 * t] = base;
  off0[2 * t + 1] = base + c0;
  curv[2 * t] = base;
  curv[2 * t + 1] = base + c0;
  __syncthreads();
  for (int i = t; i < n; i += 256) {
    unsigned p = be[i];
    int dl = p >> 17;
    int pos = atomicAdd(&curv[dl], 1);
    srclist[(size_t)b * BCAP + pos] = (int)(p & 0x1FFFF);
  }
  __syncthreads();
  int node0 = b << 9;
  for (int i = t; i < 512; i += 256) {
    int node = node0 + i;
    if (node < N_NODES) {
      offs[node] = b * BCAP + off0[i];
      degv[node] = cnt[i];
    }
  }
}

__device__ inline unsigned pack_h2(float a, float b) {
  __half2 h = __floats2half2_rn(a, b);
  return *reinterpret_cast<unsigned*>(&h);
}

// ---------------------------------------------------------------------------
// Y[row] = fp16( csrc[row] * (X[row] @ W) )   thread-per-row, W in LDS
// ---------------------------------------------------------------------------
__global__ __launch_bounds__(256) void gemm_in_h(
    const float* __restrict__ X, const float* __restrict__ W,
    const float* __restrict__ csrc, __half* __restrict__ Y) {
  __shared__ float Ws[64 * 64];
  for (int t = threadIdx.x; t < 64 * 64; t += 256) Ws[t] = W[t];
  __syncthreads();
  int row = blockIdx.x * 256 + threadIdx.x;
  if (row >= N_NODES) return;
  const float4* xr = (const float4*)(X + (size_t)row * 64);
  float acc[64];
#pragma unroll
  for (int j = 0; j < 64; j++) acc[j] = 0.0f;
#pragma unroll
  for (int k4 = 0; k4 < 16; k4++) {
    float4 xv = xr[k4];
    const float* w0 = &Ws[(k4 * 4 + 0) * 64];
    const float* w1 = &Ws[(k4 * 4 + 1) * 64];
    const float* w2 = &Ws[(k4 * 4 + 2) * 64];
    const float* w3 = &Ws[(k4 * 4 + 3) * 64];
#pragma unroll
    for (int j = 0; j < 64; j++)
      acc[j] += xv.x * w0[j] + xv.y * w1[j] + xv.z * w2[j] + xv.w * w3[j];
  }
  float s = csrc[row];
  uint4* yr = (uint4*)(Y + (size_t)row * 64);
#pragma unroll
  for (int j8 = 0; j8 < 8; j8++) {
    uint4 u;
    u.x = pack_h2(s * acc[j8 * 8 + 0], s * acc[j8 * 8 + 1]);
    u.y = pack_h2(s * acc[j8 * 8 + 2], s * acc[j8 * 8 + 3]);
    u.z = pack_h2(s * acc[j8 * 8 + 4], s * acc[j8 * 8 + 5]);
    u.w = pack_h2(s * acc[j8 * 8 + 6], s * acc[j8 * 8 + 7]);
    yr[j8] = u;
  }
}

// ---------------------------------------------------------------------------
// Packed-half accumulate: w holds 2 fp16 features; v_dot2_f32_f16 with masks
// (1,0)/(0,1) accumulates each into its f32 lane accumulator — 2 VALU ops
// per word vs 4 for cvt+cvt+add+add, identical f32 numerics (x*1.0 exact).
// ---------------------------------------------------------------------------
typedef _Float16 half2r __attribute__((ext_vector_type(2)));

__device__ inline void dacc(unsigned w, float& a, float& b) {
  half2r v = __builtin_bit_cast(half2r, w);
  const half2r m10 = {(_Float16)1.0f, (_Float16)0.0f};
  const half2r m01 = {(_Float16)0.0f, (_Float16)1.0f};
  a = __builtin_amdgcn_fdot2(v, m10, a, false);
  b = __builtin_amdgcn_fdot2(v, m01, b, false);
}

__device__ inline void dacc4(uint4 u, float* acc) {
  dacc(u.x, acc[0], acc[1]); dacc(u.y, acc[2], acc[3]);
  dacc(u.z, acc[4], acc[5]); dacc(u.w, acc[6], acc[7]);
}

// ---------------------------------------------------------------------------
// Dual-node oct-edge aggregation: wave = 2 nodes, lanes split 8 (edge slot q)
// x 8 (feature oct f, 16B). Per iteration up to FOUR independent uint4 loads
// in flight (2 per node) — 2x the memory-level parallelism of the single-node
// form; loop control, srclist reads and (in the caller) LDS W reads are
// amortized over both nodes. Butterfly-reduce over q at the end.
// ---------------------------------------------------------------------------
__device__ inline void agg_oct2(const __half* __restrict__ Y,
                                int begA, int degA, int begB, int degB,
                                const int* __restrict__ srclist, int lane,
                                int f, int q,
                                float* __restrict__ outA,
                                float* __restrict__ outB) {
  float a[8], c[8];
#pragma unroll
  for (int i = 0; i < 8; i++) { a[i] = 0.0f; c[i] = 0.0f; }
  const __half* Yl = Y + 8 * f;
  int degM = degA > degB ? degA : degB;
  for (int base = 0; base < degM; base += 64) {
    int svA = (base + lane < degA) ? srclist[begA + base + lane] : 0;
    int svB = (base + lane < degB) ? srclist[begB + base + lane] : 0;
    int chunkA = degA - base;
    chunkA = chunkA < 0 ? 0 : (chunkA > 64 ? 64 : chunkA);
    int chunkB = degB - base;
    chunkB = chunkB < 0 ? 0 : (chunkB > 64 ? 64 : chunkB);
    int nq16A = chunkA & ~15;
    int nq16B = chunkB & ~15;
    int nq16M = nq16A > nq16B ? nq16A : nq16B;
    for (int j = 0; j < nq16M; j += 16) {
      bool doA = j < nq16A;  // wave-uniform
      bool doB = j < nq16B;
      int sA0 = __shfl(svA, j + q);
      int sA1 = __shfl(svA, j + 8 + q);
      int sB0 = __shfl(svB, j + q);
      int sB1 = __shfl(svB, j + 8 + q);
      uint4 uA0, uA1, uB0, uB1;
      if (doA) {
        uA0 = *(const uint4*)(Yl + (size_t)sA0 * 64);
        uA1 = *(const uint4*)(Yl + (size_t)sA1 * 64);
      }
      if (doB) {
        uB0 = *(const uint4*)(Yl + (size_t)sB0 * 64);
        uB1 = *(const uint4*)(Yl + (size_t)sB1 * 64);
      }
      if (doA) { dacc4(uA0, a); dacc4(uA1, a); }
      if (doB) { dacc4(uB0, c); dacc4(uB1, c); }
    }
    // tails: up to 15 edges per node via 2 predicated oct steps each
    {
      int j0 = nq16A + q;
      int j1 = nq16A + 8 + q;
      int s0 = __shfl(svA, j0 & 63);
      int s1 = __shfl(svA, j1 & 63);
      int k0 = nq16B + q;
      int k1 = nq16B + 8 + q;
      int r0 = __shfl(svB, k0 & 63);
      int r1 = __shfl(svB, k1 & 63);
      if (j0 < chunkA) dacc4(*(const uint4*)(Yl + (size_t)s0 * 64), a);
      if (k0 < chunkB) dacc4(*(const uint4*)(Yl + (size_t)r0 * 64), c);
      if (j1 < chunkA) dacc4(*(const uint4*)(Yl + (size_t)s1 * 64), a);
      if (k1 < chunkB) dacc4(*(const uint4*)(Yl + (size_t)r1 * 64), c);
    }
  }
#pragma unroll
  for (int i = 0; i < 8; i++) {
    float v = a[i];
    v += __shfl_xor(v, 8);
    v += __shfl_xor(v, 16);
    v += __shfl_xor(v, 32);
    outA[i] = v;
    float w = c[i];
    w += __shfl_xor(w, 8);
    w += __shfl_xor(w, 16);
    w += __shfl_xor(w, 32);
    outB[i] = w;
  }
}

// ---------------------------------------------------------------------------
// Fused: conv1 aggregation + epilogue + conv2 input GEMM, dual-node waves.
// W1 transposed in LDS with 16B-chunk XOR swizzle; each WsT read is shared
// by BOTH nodes of the wave (halves DS traffic per node).
// ---------------------------------------------------------------------------
__global__ __launch_bounds__(256) void gather_mid(
    const __half* __restrict__ Y, const int* __restrict__ offs,
    const int* __restrict__ degv, const int* __restrict__ srclist,
    const float* __restrict__ b0, const float* __restrict__ csrc,
    const float* __restrict__ W1, __half* __restrict__ Y2) {
  __shared__ float WsT[64 * 64];  // [out][k], 16B chunk c = k4 ^ (out&7)
  __shared__ float hs[8][64];
  for (int i = threadIdx.x; i < 64 * 64; i += 256) {
    int k = i >> 6, o = i & 63;
    int c = (k >> 2) ^ (o & 7);
    WsT[o * 64 + (c << 2) + (k & 3)] = W1[i];
  }
  __syncthreads();
  int lane = threadIdx.x & 63;
  int wslot = threadIdx.x >> 6;
  int ws2 = wslot * 2;
  int f = lane & 7, q = lane >> 3;
  float4 bv0 = ((const float4*)b0)[2 * f];
  float4 bv1 = ((const float4*)b0)[2 * f + 1];
  for (int widA = blockIdx.x * 8 + ws2; widA < N_NODES; widA += AGG_STRIDE) {
    int widB = widA + 1;  // N even, widA even -> always valid
    int begA = offs[widA], degA = degv[widA];
    int begB = offs[widB], degB = degv[widB];
    float accA[8], accB[8];
    agg_oct2(Y, begA, degA, begB, degB, srclist, lane, f, q, accA, accB);
    float cdA = degA > 0 ? rsqrtf((float)degA) : 0.0f;
    float cdB = degB > 0 ? rsqrtf((float)degB) : 0.0f;
    if (lane < 8) {
      float4 h;
      h.x = fmaxf(accA[0] * cdA + bv0.x, 0.0f);
      h.y = fmaxf(accA[1] * cdA + bv0.y, 0.0f);
      h.z = fmaxf(accA[2] * cdA + bv0.z, 0.0f);
      h.w = fmaxf(accA[3] * cdA + bv0.w, 0.0f);
      *((float4*)&hs[ws2][8 * f]) = h;
      h.x = fmaxf(accA[4] * cdA + bv1.x, 0.0f);
      h.y = fmaxf(accA[5] * cdA + bv1.y, 0.0f);
      h.z = fmaxf(accA[6] * cdA + bv1.z, 0.0f);
      h.w = fmaxf(accA[7] * cdA + bv1.w, 0.0f);
      *((float4*)&hs[ws2][8 * f + 4]) = h;
      h.x = fmaxf(accB[0] * cdB + bv0.x, 0.0f);
      h.y = fmaxf(accB[1] * cdB + bv0.y, 0.0f);
      h.z = fmaxf(accB[2] * cdB + bv0.z, 0.0f);
      h.w = fmaxf(accB[3] * cdB + bv0.w, 0.0f);
      *((float4*)&hs[ws2 + 1][8 * f]) = h;
      h.x = fmaxf(accB[4] * cdB + bv1.x, 0.0f);
      h.y = fmaxf(accB[5] * cdB + bv1.y, 0.0f);
      h.z = fmaxf(accB[6] * cdB + bv1.z, 0.0f);
      h.w = fmaxf(accB[7] * cdB + bv1.w, 0.0f);
      *((float4*)&hs[ws2 + 1][8 * f + 4]) = h;
    }
    // same-wave LDS RAW: in-order DS pipe, no barrier needed
    float acc2A = 0.0f, acc2B = 0.0f;
#pragma unroll
    for (int k4 = 0; k4 < 16; k4++) {
      float4 w = *((const float4*)&WsT[lane * 64 + ((k4 ^ (lane & 7)) << 2)]);
      float4 hA = *((const float4*)&hs[ws2][4 * k4]);
      float4 hB = *((const float4*)&hs[ws2 + 1][4 * k4]);
      acc2A += hA.x * w.x + hA.y * w.y + hA.z * w.z + hA.w * w.w;
      acc2B += hB.x * w.x + hB.y * w.y + hB.z * w.z + hB.w * w.w;
    }
    Y2[(size_t)widA * 64 + lane] = __float2half(csrc[widA] * acc2A);
    Y2[(size_t)widB * 64 + lane] = __float2half(csrc[widB] * acc2B);
  }
}

// ---------------------------------------------------------------------------
// Final aggregation + epilogue into z (fp32 output), dual-node waves.
// MODE 0: z = relu(...)
// MODE 1: z -= relu(...), and emit uv[node] = {z.Wc_top(2), z.Wc_bot(2)}
// ---------------------------------------------------------------------------
template <int MODE>
__global__ __launch_bounds__(256) void gather_fin(
    const __half* __restrict__ Y2, const int* __restrict__ offs,
    const int* __restrict__ degv, const int* __restrict__ srclist,
    const float* __restrict__ b1, float* __restrict__ z,
    float* __restrict__ uv, const float* __restrict__ Wc) {
  __shared__ float Wcs[256];
  if (MODE == 1) {
    Wcs[threadIdx.x] = Wc[threadIdx.x];
    __syncthreads();
  }
  int lane = threadIdx.x & 63;
  int wslot = threadIdx.x >> 6;
  int f = lane & 7, q = lane >> 3;
  float4 bv0 = ((const float4*)b1)[2 * f];
  float4 bv1 = ((const float4*)b1)[2 * f + 1];
  for (int widA = blockIdx.x * 8 + wslot * 2; widA < N_NODES;
       widA += AGG_STRIDE) {
    int widB = widA + 1;
    int begA = offs[widA], degA = degv[widA];
    int begB = offs[widB], degB = degv[widB];
    float accA[8], accB[8];
    agg_oct2(Y2, begA, degA, begB, degB, srclist, lane, f, q, accA, accB);
#pragma unroll
    for (int node = 0; node < 2; node++) {
      int wid = node ? widB : widA;
      int deg = node ? degB : degA;
      const float* acc = node ? accB : accA;
      float cd = deg > 0 ? rsqrtf((float)deg) : 0.0f;
      float v[8];
      v[0] = fmaxf(acc[0] * cd + bv0.x, 0.0f);
      v[1] = fmaxf(acc[1] * cd + bv0.y, 0.0f);
      v[2] = fmaxf(acc[2] * cd + bv0.z, 0.0f);
      v[3] = fmaxf(acc[3] * cd + bv0.w, 0.0f);
      v[4] = fmaxf(acc[4] * cd + bv1.x, 0.0f);
      v[5] = fmaxf(acc[5] * cd + bv1.y, 0.0f);
      v[6] = fmaxf(acc[6] * cd + bv1.z, 0.0f);
      v[7] = fmaxf(acc[7] * cd + bv1.w, 0.0f);
      float* zrow = z + (size_t)wid * 64 + 8 * f;
      if (MODE == 0) {
        if (lane < 8) {
          *((float4*)zrow) = make_float4(v[0], v[1], v[2], v[3]);
          *((float4*)(zrow + 4)) = make_float4(v[4], v[5], v[6], v[7]);
        }
      } else {
        float4 zo0 = *((const float4*)zrow);
        float4 zo1 = *((const float4*)(zrow + 4));
        float r[8];
        r[0] = zo0.x - v[0]; r[1] = zo0.y - v[1];
        r[2] = zo0.z - v[2]; r[3] = zo0.w - v[3];
        r[4] = zo1.x - v[4]; r[5] = zo1.y - v[5];
        r[6] = zo1.z - v[6]; r[7] = zo1.w - v[7];
        if (lane < 8) {
          *((float4*)zrow) = make_float4(r[0], r[1], r[2], r[3]);
          *((float4*)(zrow + 4)) = make_float4(r[4], r[5], r[6], r[7]);
        }
        float pu0 = 0.0f, pu1 = 0.0f, pv0 = 0.0f, pv1 = 0.0f;
#pragma unroll
        for (int i = 0; i < 8; i++) {
          int j = 8 * f + i;
          pu0 += r[i] * Wcs[j * 2 + 0];
          pu1 += r[i] * Wcs[j * 2 + 1];
          pv0 += r[i] * Wcs[(64 + j) * 2 + 0];
          pv1 += r[i] * Wcs[(64 + j) * 2 + 1];
        }
#pragma unroll
        for (int o = 1; o < 8; o <<= 1) {
          pu0 += __shfl_xor(pu0, o);
          pu1 += __shfl_xor(pu1, o);
          pv0 += __shfl_xor(pv0, o);
          pv1 += __shfl_xor(pv1, o);
        }
        if (lane == 0) {
          float4 o4 = make_float4(pu0, pu1, pv0, pv1);
          *((float4*)(uv + (size_t)wid * 4)) = o4;
        }
      }
    }
  }
}

// ---------------------------------------------------------------------------
// probs[e] = sigmoid(u(s) + v(d) + bc)  — factorized classifier
// ---------------------------------------------------------------------------
__global__ __launch_bounds__(256) void classify_kernel(
    const float* __restrict__ uv, const int* __restrict__ ei,
    const float* __restrict__ bc, float* __restrict__ out) {
  int e = blockIdx.x * 256 + threadIdx.x;
  if (e >= E_QQ) return;
  int s = ei[e];
  int d = ei[E_QQ + e];
  float4 us = *((const float4*)(uv + (size_t)s * 4));
  float4 vd = *((const float4*)(uv + (size_t)d * 4));
  float l0 = us.x + vd.z + bc[0];
  float l1 = us.y + vd.w + bc[1];
  float2 o;
  o.x = 1.0f / (1.0f + __expf(-l0));
  o.y = 1.0f / (1.0f + __expf(-l1));
  *((float2*)(out + (size_t)e * 2)) = o;
}

extern "C" void kernel_launch(void* const* d_in, const int* in_sizes, int n_in,
                              void* d_out, int out_size, void* d_ws,
                              size_t ws_size, hipStream_t stream) {
  const float* x   = (const float*)d_in[0];
  const float* W0p = (const float*)d_in[1];
  const float* b0p = (const float*)d_in[2];
  const float* W0n = (const float*)d_in[3];
  const float* b0n = (const float*)d_in[4];
  const float* W1p = (const float*)d_in[5];
  const float* b1p = (const float*)d_in[6];
  const float* W1n = (const float*)d_in[7];
  const float* b1n = (const float*)d_in[8];
  const float* Wc  = (const float*)d_in[9];
  const float* bc  = (const float*)d_in[10];
  const int* sp = (const int*)d_in[11];
  const int* dp = (const int*)d_in[12];
  const int* sn = (const int*)d_in[13];
  const int* dn = (const int*)d_in[14];
  const int* ei = (const int*)d_in[15];

  // workspace layout (~53 MB)
  float* csrc_p = (float*)d_ws;                       // N
  float* csrc_n = csrc_p + N_NODES;                   // N
  int* offs_p = (int*)(csrc_n + N_NODES);             // N
  int* deg_p  = offs_p + N_NODES;                     // N
  int* offs_n = deg_p + N_NODES;                      // N
  int* deg_n  = offs_n + N_NODES;                     // N
  float* uv   = (float*)(deg_n + N_NODES);            // 4N
  int* gcur   = (int*)(uv + 4 * N_NODES);             // 2*NBUCK (+pad)
  unsigned* bin_d = (unsigned*)(gcur + 2 * NBUCK + 2);       // NBUCK*BCAP
  unsigned* bin_s = bin_d + (size_t)NBUCK * BCAP;            // NBUCK*BCAP
  int* srclist = (int*)(bin_s + (size_t)NBUCK * BCAP);       // NBUCK*BCAP
  __half* A = (__half*)(srclist + (size_t)NBUCK * BCAP);     // N*64 fp16
  __half* B = A + (size_t)N_NODES * 64;                      // N*64 fp16

  float* z     = (float*)d_out;                   // N*64 fp32
  float* probs = z + (size_t)N_NODES * 64;        // E_Q*2 fp32

  int* gcur_d = gcur;
  int* gcur_s = gcur + NBUCK;

  const int gemmGrid = (N_NODES + 255) / 256;

  // ---- POS relation ----
  hipMemsetAsync(gcur, 0, 2 * NBUCK * sizeof(int), stream);
  bin_edges<<<P1_BLOCKS, 256, 0, stream>>>(sp, dp, gcur_d, gcur_s, bin_d, bin_s);
  build_tables<<<2 * NBUCK, 256, 0, stream>>>(bin_d, gcur_d, bin_s, gcur_s,
                                              offs_p, deg_p, srclist, csrc_p);
  gemm_in_h<<<gemmGrid, 256, 0, stream>>>(x, W0p, csrc_p, A);
  gather_mid<<<AGG_BLOCKS, 256, 0, stream>>>(A, offs_p, deg_p, srclist, b0p,
                                             csrc_p, W1p, B);
  gather_fin<0><<<AGG_BLOCKS, 256, 0, stream>>>(B, offs_p, deg_p, srclist, b1p,
                                                z, uv, Wc);

  // ---- NEG relation ---- (bins/srclist reused; pos consumers done)
  hipMemsetAsync(gcur, 0, 2 * NBUCK * sizeof(int), stream);
  bin_edges<<<P1_BLOCKS, 256, 0, stream>>>(sn, dn, gcur_d, gcur_s, bin_d, bin_s);
  build_tables<<<2 * NBUCK, 256, 0, stream>>>(bin_d, gcur_d, bin_s, gcur_s,
                                              offs_n, deg_n, srclist, csrc_n);
  gemm_in_h<<<gemmGrid, 256, 0, stream>>>(x, W0n, csrc_n, A);
  gather_mid<<<AGG_BLOCKS, 256, 0, stream>>>(A, offs_n, deg_n, srclist, b0n,
                                             csrc_n, W1n, B);
  gather_fin<1><<<AGG_BLOCKS, 256, 0, stream>>>(B, offs_n, deg_n, srclist, b1n,
                                                z, uv, Wc);

  // ---- classifier (factorized) ----
  classify_kernel<<<(E_QQ + 255) / 256, 256, 0, stream>>>(uv, ei, bc, probs);
}